// Round 1
// baseline (380.221 us; speedup 1.0000x reference)
//
#include <hip/hip_runtime.h>
#include <hip/hip_bf16.h>
#include <cstdint>
#include <cstddef>

#define DMODEL 1024
#define NHEADS 16
#define DK 64
#define SEQ 2048
#define BATCH 2

typedef short bf16x8 __attribute__((ext_vector_type(8)));
typedef float f32x4 __attribute__((ext_vector_type(4)));

typedef const __attribute__((address_space(1))) void* gas_ptr;
typedef __attribute__((address_space(3))) void* las_ptr;

__device__ __forceinline__ void gld_lds16(const void* g, void* l) {
    __builtin_amdgcn_global_load_lds((gas_ptr)g, (las_ptr)l, 16, 0, 0);
}

__device__ __forceinline__ ushort f2bf_u(float f) {
    uint32_t x = __float_as_uint(f);
    x += 0x7fff + ((x >> 16) & 1);   // RNE
    return (ushort)(x >> 16);
}

// ---------------- cast fp32 -> bf16 (vectorized) ----------------
__global__ __launch_bounds__(256) void cast_f32_bf16(
        const float* __restrict__ src, ushort* __restrict__ dst, int n) {
    int i = (blockIdx.x * 256 + threadIdx.x) * 4;
    if (i >= n) return;
    float4 f = *reinterpret_cast<const float4*>(src + i);
    ushort4 o;
    o.x = f2bf_u(f.x); o.y = f2bf_u(f.y); o.z = f2bf_u(f.z); o.w = f2bf_u(f.w);
    *reinterpret_cast<ushort4*>(dst + i) = o;
}

// ---------------- GEMM: C[m][n] = sum_k A[m][k] * W[n][k] + bias[n] ----------------
// m97 structure: 128x128 tile, BK=32, 4 waves (2x2), acc 4x4 frags of 16x16x32 bf16.
// MODE 0: bf16 out, (B,H,S,DK) layout   (Q,K projections)
// MODE 1: bf16 out, (B,H,DK,S) layout   (V projection, transposed for PV)
// MODE 2: f32 out, row-major [M][N]     (output projection)
template<int MODE>
__global__ __launch_bounds__(256) void gemm_bt(
        const ushort* __restrict__ A,   // M x K bf16 row-major
        const ushort* __restrict__ W,   // N x K bf16 row-major
        const float* __restrict__ bias, // N
        void* __restrict__ out, int M, int N, int K) {
    __shared__ ushort As[128 * 32];
    __shared__ ushort Bs[128 * 32];
    const int tid = threadIdx.x;
    const int w = tid >> 6, lane = tid & 63;
    const int lr = lane & 15, lg = lane >> 4;
    const int nTiles = N >> 7;
    const int tM = (blockIdx.x / nTiles) << 7;
    const int tN = (blockIdx.x % nTiles) << 7;
    const int wr = (w >> 1) * 64, wc = (w & 1) * 64;

    f32x4 acc[4][4] = {};

    // staging: chunk c = (w*2+i)*64 + lane covers LDS bytes [c*16, c*16+16)
    // row = c>>2 (64B rows), col-chunk = c&3 (8 bf16 each)
    const int c0 = (w * 2 + 0) * 64 + lane;
    const int c1 = (w * 2 + 1) * 64 + lane;
    const ushort* gA0 = A + (size_t)(tM + (c0 >> 2)) * K + (c0 & 3) * 8;
    const ushort* gA1 = A + (size_t)(tM + (c1 >> 2)) * K + (c1 & 3) * 8;
    const ushort* gB0 = W + (size_t)(tN + (c0 >> 2)) * K + (c0 & 3) * 8;
    const ushort* gB1 = W + (size_t)(tN + (c1 >> 2)) * K + (c1 & 3) * 8;
    ushort* lA0 = As + (w * 2 + 0) * 512;
    ushort* lA1 = As + (w * 2 + 1) * 512;
    ushort* lB0 = Bs + (w * 2 + 0) * 512;
    ushort* lB1 = Bs + (w * 2 + 1) * 512;

    for (int k0 = 0; k0 < K; k0 += 32) {
        gld_lds16(gA0 + k0, lA0);
        gld_lds16(gA1 + k0, lA1);
        gld_lds16(gB0 + k0, lB0);
        gld_lds16(gB1 + k0, lB1);
        __syncthreads();

        bf16x8 af[4], bfr[4];
#pragma unroll
        for (int i = 0; i < 4; i++)
            af[i] = *(const bf16x8*)(As + (wr + i * 16 + lr) * 32 + lg * 8);
#pragma unroll
        for (int i = 0; i < 4; i++)
            bfr[i] = *(const bf16x8*)(Bs + (wc + i * 16 + lr) * 32 + lg * 8);
#pragma unroll
        for (int mi = 0; mi < 4; mi++)
#pragma unroll
            for (int ni = 0; ni < 4; ni++)
                acc[mi][ni] = __builtin_amdgcn_mfma_f32_16x16x32_bf16(
                    af[mi], bfr[ni], acc[mi][ni], 0, 0, 0);
        __syncthreads();
    }

    // epilogue: D layout col=lane&15, row=(lane>>4)*4+r  [verified m89/m91]
#pragma unroll
    for (int mi = 0; mi < 4; mi++) {
        const int row0 = tM + wr + mi * 16 + lg * 4;
#pragma unroll
        for (int ni = 0; ni < 4; ni++) {
            const int col = tN + wc + ni * 16 + lr;
            const float bv = bias[col];
#pragma unroll
            for (int r = 0; r < 4; r++) {
                float vv = acc[mi][ni][r] + bv;
                int m = row0 + r;
                if (MODE == 2) {
                    ((float*)out)[(size_t)m * N + col] = vv;
                } else {
                    int b = m >> 11, s = m & (SEQ - 1);
                    int h = col >> 6, d = col & (DK - 1);
                    if (MODE == 0)
                        ((ushort*)out)[(((size_t)(b * NHEADS + h) * SEQ + s) * DK) + d] = f2bf_u(vv);
                    else
                        ((ushort*)out)[(((size_t)(b * NHEADS + h) * DK + d) * SEQ) + s] = f2bf_u(vv);
                }
            }
        }
    }
}

// ---------------- flash attention: 1 wave per 16 q-rows ----------------
// Qh,Kh: (B,H,S,DK) bf16.  Vt: (B,H,DK,S) bf16.  ctx out: (B,S,DMODEL) bf16.
__global__ __launch_bounds__(64) void attn_fwd(
        const ushort* __restrict__ Qh, const ushort* __restrict__ Kh,
        const ushort* __restrict__ Vt, const int* __restrict__ mask,
        ushort* __restrict__ ctx) {
    __shared__ ushort P[16 * 32];
    const int lane = threadIdx.x;
    const int lr = lane & 15, lg = lane >> 4;
    const int qt = blockIdx.x & (SEQ / 16 - 1);
    const int bh = blockIdx.x >> 7;           // SEQ/16 = 128 q-tiles
    const int b = bh >> 4, h = bh & 15;
    const int q0 = qt * 16;

    const ushort* Qbase = Qh + ((size_t)bh * SEQ + q0) * DK;
    const ushort* Kbase = Kh + (size_t)bh * SEQ * DK;
    const ushort* Vbase = Vt + (size_t)bh * DK * SEQ;
    const int* mrow = mask + b * SEQ;

    // Q A-frags: lane holds Q[q0 + lr][kk*32 + lg*8 .. +8]
    bf16x8 aq0 = *(const bf16x8*)(Qbase + lr * DK + lg * 8);
    bf16x8 aq1 = *(const bf16x8*)(Qbase + lr * DK + 32 + lg * 8);

    f32x4 cacc[4] = {};           // 4 d-chunks of 16; row=(lg*4+r), col=lr
    float mrun[4], lrun[4];
#pragma unroll
    for (int r = 0; r < 4; r++) { mrun[r] = -1e30f; lrun[r] = 0.f; }

    for (int kv0 = 0; kv0 < SEQ; kv0 += 32) {
        // scores: 2 tiles of 16 cols
        f32x4 s[2];
#pragma unroll
        for (int c = 0; c < 2; c++) {
            const ushort* kp = Kbase + (size_t)(kv0 + c * 16 + lr) * DK + lg * 8;
            bf16x8 bk0 = *(const bf16x8*)(kp);
            bf16x8 bk1 = *(const bf16x8*)(kp + 32);
            f32x4 z = {};
            z = __builtin_amdgcn_mfma_f32_16x16x32_bf16(aq0, bk0, z, 0, 0, 0);
            z = __builtin_amdgcn_mfma_f32_16x16x32_bf16(aq1, bk1, z, 0, 0, 0);
            s[c] = z;
        }
        // scale + mask (col = kv0 + c*16 + lr, uniform across regs)
        const int mk0 = mrow[kv0 + lr];
        const int mk1 = mrow[kv0 + 16 + lr];
#pragma unroll
        for (int r = 0; r < 4; r++) {
            s[0][r] = mk0 ? s[0][r] * 0.125f : -1e9f;
            s[1][r] = mk1 ? s[1][r] * 0.125f : -1e9f;
        }
        // row-max over 32 cols: per-reg pairwise, then 16-lane butterfly
        float mc[4];
#pragma unroll
        for (int r = 0; r < 4; r++) mc[r] = fmaxf(s[0][r], s[1][r]);
#pragma unroll
        for (int off = 8; off >= 1; off >>= 1)
#pragma unroll
            for (int r = 0; r < 4; r++) mc[r] = fmaxf(mc[r], __shfl_xor(mc[r], off));

        float alpha[4];
#pragma unroll
        for (int r = 0; r < 4; r++) {
            float mnew = fmaxf(mrun[r], mc[r]);
            alpha[r] = __expf(mrun[r] - mnew);
            mrun[r] = mnew;
        }
        float rs[4];
#pragma unroll
        for (int r = 0; r < 4; r++) {
            s[0][r] = __expf(s[0][r] - mrun[r]);
            s[1][r] = __expf(s[1][r] - mrun[r]);
            rs[r] = s[0][r] + s[1][r];
        }
#pragma unroll
        for (int off = 8; off >= 1; off >>= 1)
#pragma unroll
            for (int r = 0; r < 4; r++) rs[r] += __shfl_xor(rs[r], off);
#pragma unroll
        for (int r = 0; r < 4; r++) lrun[r] = lrun[r] * alpha[r] + rs[r];
        // rescale running context
#pragma unroll
        for (int dc = 0; dc < 4; dc++)
#pragma unroll
            for (int r = 0; r < 4; r++) cacc[dc][r] *= alpha[r];
        // P tile -> LDS (row = q row, col = kv within tile)
#pragma unroll
        for (int c = 0; c < 2; c++)
#pragma unroll
            for (int r = 0; r < 4; r++)
                P[(lg * 4 + r) * 32 + c * 16 + lr] = f2bf_u(s[c][r]);
        __syncthreads();
        bf16x8 ap = *(const bf16x8*)(P + lr * 32 + lg * 8);
        // PV: ctx[q][d] += sum_kv P[q][kv] * V[kv][d]; B-frag from Vt (K-contig)
#pragma unroll
        for (int dc = 0; dc < 4; dc++) {
            const ushort* vp = Vbase + (size_t)(dc * 16 + lr) * SEQ + kv0 + lg * 8;
            bf16x8 bv = *(const bf16x8*)vp;
            cacc[dc] = __builtin_amdgcn_mfma_f32_16x16x32_bf16(ap, bv, cacc[dc], 0, 0, 0);
        }
        __syncthreads();
    }
    // epilogue: divide by l, write (B,S,DMODEL) bf16
#pragma unroll
    for (int dc = 0; dc < 4; dc++)
#pragma unroll
        for (int r = 0; r < 4; r++) {
            float vv = cacc[dc][r] / lrun[r];
            int row = q0 + lg * 4 + r;
            int d = dc * 16 + lr;
            ctx[((size_t)(b * SEQ + row)) * DMODEL + h * DK + d] = f2bf_u(vv);
        }
}

extern "C" void kernel_launch(void* const* d_in, const int* in_sizes, int n_in,
                              void* d_out, int out_size, void* d_ws, size_t ws_size,
                              hipStream_t stream) {
    const float* q    = (const float*)d_in[0];
    const float* k    = (const float*)d_in[1];
    const float* v    = (const float*)d_in[2];
    const int*   mask = (const int*)d_in[3];
    const float* Wq   = (const float*)d_in[4];
    const float* bq   = (const float*)d_in[5];
    const float* Wk   = (const float*)d_in[6];
    const float* bk   = (const float*)d_in[7];
    const float* Wv   = (const float*)d_in[8];
    const float* bv   = (const float*)d_in[9];
    const float* Wo   = (const float*)d_in[10];
    const float* bo   = (const float*)d_in[11];

    char* ws = (char*)d_ws;
    ushort* qb   = (ushort*)(ws + (size_t)0);
    ushort* kb   = (ushort*)(ws + ((size_t)8  << 20));
    ushort* vb   = (ushort*)(ws + ((size_t)16 << 20));
    ushort* Wqb  = (ushort*)(ws + ((size_t)24 << 20));
    ushort* Wkb  = (ushort*)(ws + ((size_t)26 << 20));
    ushort* Wvb  = (ushort*)(ws + ((size_t)28 << 20));
    ushort* Wob  = (ushort*)(ws + ((size_t)30 << 20));
    ushort* Qh   = (ushort*)(ws + ((size_t)32 << 20));
    ushort* Kh   = (ushort*)(ws + ((size_t)40 << 20));
    ushort* Vt   = (ushort*)(ws + ((size_t)48 << 20));
    ushort* ctxb = (ushort*)(ws + ((size_t)56 << 20));

    const int nQKV = BATCH * SEQ * DMODEL;   // 4194304
    const int nW   = DMODEL * DMODEL;        // 1048576
    cast_f32_bf16<<<nQKV / 1024, 256, 0, stream>>>(q,  qb,  nQKV);
    cast_f32_bf16<<<nQKV / 1024, 256, 0, stream>>>(k,  kb,  nQKV);
    cast_f32_bf16<<<nQKV / 1024, 256, 0, stream>>>(v,  vb,  nQKV);
    cast_f32_bf16<<<nW   / 1024, 256, 0, stream>>>(Wq, Wqb, nW);
    cast_f32_bf16<<<nW   / 1024, 256, 0, stream>>>(Wk, Wkb, nW);
    cast_f32_bf16<<<nW   / 1024, 256, 0, stream>>>(Wv, Wvb, nW);
    cast_f32_bf16<<<nW   / 1024, 256, 0, stream>>>(Wo, Wob, nW);

    const int M = BATCH * SEQ;               // 4096
    const int gemmGrid = (M / 128) * (DMODEL / 128);   // 256
    gemm_bt<0><<<gemmGrid, 256, 0, stream>>>(qb, Wqb, bq, Qh, M, DMODEL, DMODEL);
    gemm_bt<0><<<gemmGrid, 256, 0, stream>>>(kb, Wkb, bk, Kh, M, DMODEL, DMODEL);
    gemm_bt<1><<<gemmGrid, 256, 0, stream>>>(vb, Wvb, bv, Vt, M, DMODEL, DMODEL);

    attn_fwd<<<BATCH * NHEADS * (SEQ / 16), 64, 0, stream>>>(Qh, Kh, Vt, mask, ctxb);

    gemm_bt<2><<<gemmGrid, 256, 0, stream>>>(ctxb, Wob, bo, (void*)d_out, M, DMODEL, DMODEL);
}

// Round 2
// 234.207 us; speedup vs baseline: 1.6234x; 1.6234x over previous
//
#include <hip/hip_runtime.h>
#include <hip/hip_bf16.h>
#include <cstdint>
#include <cstddef>

#define DMODEL 1024
#define NHEADS 16
#define DK 64
#define SEQ 2048
#define BATCH 2

typedef short bf16x8 __attribute__((ext_vector_type(8)));
typedef float f32x4 __attribute__((ext_vector_type(4)));
typedef float f32x16 __attribute__((ext_vector_type(16)));
typedef unsigned int u32x4 __attribute__((ext_vector_type(4)));

typedef const __attribute__((address_space(1))) void* gas_ptr;
typedef __attribute__((address_space(3))) void* las_ptr;

__device__ __forceinline__ void gld_lds16(const void* g, void* l) {
    __builtin_amdgcn_global_load_lds((gas_ptr)g, (las_ptr)l, 16, 0, 0);
}

__device__ __forceinline__ ushort f2bf_u(float f) {
    uint32_t x = __float_as_uint(f);
    x += 0x7fff + ((x >> 16) & 1);   // RNE
    return (ushort)(x >> 16);
}

// ---------------- fused cast fp32 -> bf16 (7 arrays, 1 launch) ----------------
__global__ __launch_bounds__(256) void cast_all(
        const float* __restrict__ q, const float* __restrict__ k,
        const float* __restrict__ v, const float* __restrict__ Wq,
        const float* __restrict__ Wk, const float* __restrict__ Wv,
        const float* __restrict__ Wo,
        ushort* __restrict__ qb, ushort* __restrict__ kb, ushort* __restrict__ vb,
        ushort* __restrict__ Wqb, ushort* __restrict__ Wkb,
        ushort* __restrict__ Wvb, ushort* __restrict__ Wob) {
    int bid = blockIdx.x;
    const float* src; ushort* dst; int base;
    if      (bid <  4096) { src = q;  dst = qb;  base = bid; }
    else if (bid <  8192) { src = k;  dst = kb;  base = bid - 4096; }
    else if (bid < 12288) { src = v;  dst = vb;  base = bid - 8192; }
    else if (bid < 13312) { src = Wq; dst = Wqb; base = bid - 12288; }
    else if (bid < 14336) { src = Wk; dst = Wkb; base = bid - 13312; }
    else if (bid < 15360) { src = Wv; dst = Wvb; base = bid - 14336; }
    else                  { src = Wo; dst = Wob; base = bid - 15360; }
    int i = base * 1024 + threadIdx.x * 4;
    float4 f = *reinterpret_cast<const float4*>(src + i);
    ushort4 o;
    o.x = f2bf_u(f.x); o.y = f2bf_u(f.y); o.z = f2bf_u(f.z); o.w = f2bf_u(f.w);
    *reinterpret_cast<ushort4*>(dst + i) = o;
}

// ---------------- GEMM: C[m][n] = sum_k A[m][k] * W[n][k] + bias[n] ----------------
// 64x128 tile, BK=32, 4 waves (2x2), wave-tile 32x64, acc 2x4 frags of 16x16x32 bf16.
// MODE 0: bf16 out, (B,H,S,DK)   MODE 1: bf16 out, (B,H,DK,S)   MODE 2: f32 row-major
template<int MODE>
__global__ __launch_bounds__(256) void gemm_bt(
        const ushort* __restrict__ A,   // M x K bf16 row-major
        const ushort* __restrict__ W,   // N x K bf16 row-major
        const float* __restrict__ bias, // N
        void* __restrict__ out, int M, int N, int K) {
    __shared__ ushort As[64 * 32];
    __shared__ ushort Bs[128 * 32];
    const int tid = threadIdx.x;
    const int w = tid >> 6, lane = tid & 63;
    const int lr = lane & 15, lg = lane >> 4;
    const int nTiles = N >> 7;                 // 8
    // XCD-chunked swizzle (grid 512, 512%8==0 -> bijective)
    const int nwg = gridDim.x;
    const int cpx = nwg >> 3;
    int lid = (blockIdx.x & 7) * cpx + (blockIdx.x >> 3);
    const int tM = (lid / nTiles) << 6;
    const int tN = (lid % nTiles) << 7;
    const int wr = (w >> 1) * 32, wc = (w & 1) * 64;

    f32x4 acc[2][4] = {};

    // staging: A chunk c = w*64 + lane (1 per thread), B chunks c = w*128 + i*64 + lane
    const int cA = w * 64 + lane;
    const int cB0 = w * 128 + lane;
    const int cB1 = w * 128 + 64 + lane;
    const ushort* gA  = A + (size_t)(tM + (cA  >> 2)) * K + (cA  & 3) * 8;
    const ushort* gB0 = W + (size_t)(tN + (cB0 >> 2)) * K + (cB0 & 3) * 8;
    const ushort* gB1 = W + (size_t)(tN + (cB1 >> 2)) * K + (cB1 & 3) * 8;
    ushort* lA  = As + w * 512;
    ushort* lB0 = Bs + w * 1024;
    ushort* lB1 = Bs + w * 1024 + 512;

    for (int k0 = 0; k0 < K; k0 += 32) {
        gld_lds16(gA  + k0, lA);
        gld_lds16(gB0 + k0, lB0);
        gld_lds16(gB1 + k0, lB1);
        __syncthreads();

        bf16x8 af[2], bfr[4];
#pragma unroll
        for (int i = 0; i < 2; i++)
            af[i] = *(const bf16x8*)(As + (wr + i * 16 + lr) * 32 + lg * 8);
#pragma unroll
        for (int i = 0; i < 4; i++)
            bfr[i] = *(const bf16x8*)(Bs + (wc + i * 16 + lr) * 32 + lg * 8);
#pragma unroll
        for (int mi = 0; mi < 2; mi++)
#pragma unroll
            for (int ni = 0; ni < 4; ni++)
                acc[mi][ni] = __builtin_amdgcn_mfma_f32_16x16x32_bf16(
                    af[mi], bfr[ni], acc[mi][ni], 0, 0, 0);
        __syncthreads();
    }

    // epilogue: D layout col=lane&15, row=(lane>>4)*4+r
#pragma unroll
    for (int mi = 0; mi < 2; mi++) {
        const int row0 = tM + wr + mi * 16 + lg * 4;
#pragma unroll
        for (int ni = 0; ni < 4; ni++) {
            const int col = tN + wc + ni * 16 + lr;
            const float bv = bias[col];
#pragma unroll
            for (int r = 0; r < 4; r++) {
                float vv = acc[mi][ni][r] + bv;
                int m = row0 + r;
                if (MODE == 2) {
                    ((float*)out)[(size_t)m * N + col] = vv;
                } else {
                    int b = m >> 11, s = m & (SEQ - 1);
                    int h = col >> 6, d = col & (DK - 1);
                    if (MODE == 0)
                        ((ushort*)out)[(((size_t)(b * NHEADS + h) * SEQ + s) * DK) + d] = f2bf_u(vv);
                    else
                        ((ushort*)out)[(((size_t)(b * NHEADS + h) * DK + d) * SEQ) + s] = f2bf_u(vv);
                }
            }
        }
    }
}

// ---------------- attention: swapped-QK 32x32, in-register softmax ----------------
// Qh,Kh: (B,H,S,DK) bf16.  Vt: (B,H,DK,S) bf16.  ctx out: (B,S,DMODEL) bf16.
// Block = 4 independent waves; wave owns 32 q-rows; KVBLK=32; no LDS, no barriers.
// Swapped QK^T: lane l owns q = l&31; reg r of S^T holds kv = crow(r, l>>5),
//   crow(r,hi) = (r&3) + 8*(r>>2) + 4*hi   [m74/m101 verified 32x32 C/D layout]

// pack 8 crow-ordered exp'd P values into the PV A-frag for one 16-kv slot (T12)
__device__ __forceinline__ bf16x8 pack_pa(const float* p) {
    uint a, b, c, d;
    asm("v_cvt_pk_bf16_f32 %0, %1, %2" : "=v"(a) : "v"(p[0]), "v"(p[1]));
    asm("v_cvt_pk_bf16_f32 %0, %1, %2" : "=v"(b) : "v"(p[4]), "v"(p[5]));
    asm("v_cvt_pk_bf16_f32 %0, %1, %2" : "=v"(c) : "v"(p[2]), "v"(p[3]));
    asm("v_cvt_pk_bf16_f32 %0, %1, %2" : "=v"(d) : "v"(p[6]), "v"(p[7]));
    // a.hi <-> b.lo : a = {kv0,1 | kv8,9}, b = {kv4,5 | kv12,13}
    asm("v_permlane32_swap_b32 %0, %1" : "+v"(a), "+v"(b));
    asm("v_permlane32_swap_b32 %0, %1" : "+v"(c), "+v"(d));
    union { u32x4 u; bf16x8 h; } cv;
    cv.u = (u32x4){a, c, b, d};
    return cv.h;
}

__global__ __launch_bounds__(256) void attn_fwd32(
        const ushort* __restrict__ Qh, const ushort* __restrict__ Kh,
        const ushort* __restrict__ Vt, const int* __restrict__ mask,
        ushort* __restrict__ ctx) {
    const int w = threadIdx.x >> 6;
    const int l = threadIdx.x & 63;
    const int q32 = l & 31, hi = l >> 5;

    // XCD-chunked swizzle: 512 blocks, 64 per XCD -> ~4 heads' K/V per XCD L2
    int lid = (blockIdx.x & 7) * 64 + (blockIdx.x >> 3);
    const int qblk = lid & 15;       // 16 q-blocks of 128 per (b,h)
    const int bh = lid >> 4;         // 32
    const int b = bh >> 4, h = bh & 15;
    const int q0 = qblk * 128 + w * 32;

    const ushort* Qbase = Qh + (size_t)bh * SEQ * DK;
    const ushort* Kbase = Kh + (size_t)bh * SEQ * DK;
    const ushort* Vbase = Vt + (size_t)bh * DK * SEQ;
    const int* mrow = mask + b * SEQ;

    // Q b-frags: lane l holds Q[q0+q32][dc*16 + hi*8 .. +8]
    bf16x8 qf[4];
#pragma unroll
    for (int dc = 0; dc < 4; dc++)
        qf[dc] = *(const bf16x8*)(Qbase + (size_t)(q0 + q32) * DK + dc * 16 + hi * 8);

    f32x16 c0 = {}, c1 = {};         // ctx^? acc: row q=crow(r,hi), col d = dt*32+q32
    float mrun = -1e30f, lrun = 0.f;

    for (int kv0 = 0; kv0 < SEQ; kv0 += 32) {
        // ---- QK^T (swapped): S^T[kv][q] ----
        f32x16 s = {};
#pragma unroll
        for (int dc = 0; dc < 4; dc++) {
            bf16x8 kf = *(const bf16x8*)(Kbase + (size_t)(kv0 + q32) * DK + dc * 16 + hi * 8);
            s = __builtin_amdgcn_mfma_f32_32x32x16_bf16(kf, qf[dc], s, 0, 0, 0);
        }
        // ---- scale + mask ----
        int4 mk[4];
#pragma unroll
        for (int g = 0; g < 4; g++)
            mk[g] = *reinterpret_cast<const int4*>(mrow + kv0 + g * 8 + hi * 4);
        float p[16];
#pragma unroll
        for (int r = 0; r < 16; r++) {
            int mv = reinterpret_cast<const int*>(&mk[r >> 2])[r & 3];
            p[r] = mv ? s[r] * 0.125f : -1e9f;
        }
        // ---- tile max (per-lane over 16 regs + cross-half) ----
        float pm = p[0];
#pragma unroll
        for (int r = 1; r < 16; r++) pm = fmaxf(pm, p[r]);
        pm = fmaxf(pm, __shfl_xor(pm, 32));
        // ---- defer-max rescale (T13, THR=8) ----
        if (__any(pm - mrun > 8.0f)) {
            float mnew = fmaxf(mrun, pm);
            float alpha = __expf(mrun - mnew);
            mrun = mnew;
            lrun *= alpha;
            float aT[16];
#pragma unroll
            for (int r = 0; r < 16; r++)
                aT[r] = __shfl(alpha, (r & 3) + 8 * (r >> 2) + 4 * hi);
#pragma unroll
            for (int r = 0; r < 16; r++) { c0[r] *= aT[r]; c1[r] *= aT[r]; }
        }
        // ---- exp + row-sum ----
        float rs = 0.f;
#pragma unroll
        for (int r = 0; r < 16; r++) { p[r] = __expf(p[r] - mrun); rs += p[r]; }
        rs += __shfl_xor(rs, 32);
        lrun += rs;
        // ---- P -> bf16 A-frags (in-register, T12) ----
        bf16x8 pa0 = pack_pa(p);
        bf16x8 pa1 = pack_pa(p + 8);
        // ---- PV: ctx[q][d] += P[q][kv] * V[kv][d] ----
#pragma unroll
        for (int ks = 0; ks < 2; ks++) {
            bf16x8 v0 = *(const bf16x8*)(Vbase + (size_t)(q32)      * SEQ + kv0 + ks * 16 + hi * 8);
            bf16x8 v1 = *(const bf16x8*)(Vbase + (size_t)(32 + q32) * SEQ + kv0 + ks * 16 + hi * 8);
            bf16x8 pa = ks ? pa1 : pa0;
            c0 = __builtin_amdgcn_mfma_f32_32x32x16_bf16(pa, v0, c0, 0, 0, 0);
            c1 = __builtin_amdgcn_mfma_f32_32x32x16_bf16(pa, v1, c1, 0, 0, 0);
        }
    }

    // ---- epilogue: divide by l (transposed via shfl), coalesced bf16 stores ----
    float rl = 1.0f / lrun;
#pragma unroll
    for (int r = 0; r < 16; r++) {
        int crow = (r & 3) + 8 * (r >> 2) + 4 * hi;
        float rlT = __shfl(rl, crow);
        int qq = q0 + crow;
        size_t base = (size_t)(b * SEQ + qq) * DMODEL + h * DK;
        ctx[base + q32]      = f2bf_u(c0[r] * rlT);
        ctx[base + 32 + q32] = f2bf_u(c1[r] * rlT);
    }
}

extern "C" void kernel_launch(void* const* d_in, const int* in_sizes, int n_in,
                              void* d_out, int out_size, void* d_ws, size_t ws_size,
                              hipStream_t stream) {
    const float* q    = (const float*)d_in[0];
    const float* k    = (const float*)d_in[1];
    const float* v    = (const float*)d_in[2];
    const int*   mask = (const int*)d_in[3];
    const float* Wq   = (const float*)d_in[4];
    const float* bq   = (const float*)d_in[5];
    const float* Wk   = (const float*)d_in[6];
    const float* bk   = (const float*)d_in[7];
    const float* Wv   = (const float*)d_in[8];
    const float* bv   = (const float*)d_in[9];
    const float* Wo   = (const float*)d_in[10];
    const float* bo   = (const float*)d_in[11];

    char* ws = (char*)d_ws;
    ushort* qb   = (ushort*)(ws + (size_t)0);
    ushort* kb   = (ushort*)(ws + ((size_t)8  << 20));
    ushort* vb   = (ushort*)(ws + ((size_t)16 << 20));
    ushort* Wqb  = (ushort*)(ws + ((size_t)24 << 20));
    ushort* Wkb  = (ushort*)(ws + ((size_t)26 << 20));
    ushort* Wvb  = (ushort*)(ws + ((size_t)28 << 20));
    ushort* Wob  = (ushort*)(ws + ((size_t)30 << 20));
    ushort* Qh   = (ushort*)(ws + ((size_t)32 << 20));
    ushort* Kh   = (ushort*)(ws + ((size_t)40 << 20));
    ushort* Vt   = (ushort*)(ws + ((size_t)48 << 20));
    ushort* ctxb = (ushort*)(ws + ((size_t)56 << 20));

    cast_all<<<16384, 256, 0, stream>>>(q, k, v, Wq, Wk, Wv, Wo,
                                        qb, kb, vb, Wqb, Wkb, Wvb, Wob);

    const int M = BATCH * SEQ;                        // 4096
    const int gemmGrid = (M / 64) * (DMODEL / 128);   // 512
    gemm_bt<0><<<gemmGrid, 256, 0, stream>>>(qb, Wqb, bq, Qh, M, DMODEL, DMODEL);
    gemm_bt<0><<<gemmGrid, 256, 0, stream>>>(kb, Wkb, bk, Kh, M, DMODEL, DMODEL);
    gemm_bt<1><<<gemmGrid, 256, 0, stream>>>(vb, Wvb, bv, Vt, M, DMODEL, DMODEL);

    attn_fwd32<<<BATCH * NHEADS * (SEQ / 128), 256, 0, stream>>>(Qh, Kh, Vt, mask, ctxb);

    gemm_bt<2><<<gemmGrid, 256, 0, stream>>>(ctxb, Wob, bo, (void*)d_out, M, DMODEL, DMODEL);
}

// Round 3
// 230.531 us; speedup vs baseline: 1.6493x; 1.0159x over previous
//
#include <hip/hip_runtime.h>
#include <hip/hip_bf16.h>
#include <cstdint>
#include <cstddef>

#define DMODEL 1024
#define NHEADS 16
#define DK 64
#define SEQ 2048
#define BATCH 2
#define NT (SEQ / 32)

typedef short bf16x8 __attribute__((ext_vector_type(8)));
typedef float f32x4 __attribute__((ext_vector_type(4)));
typedef float f32x16 __attribute__((ext_vector_type(16)));
typedef unsigned int u32x4 __attribute__((ext_vector_type(4)));

typedef const __attribute__((address_space(1))) void* gas_ptr;
typedef __attribute__((address_space(3))) void* las_ptr;

__device__ __forceinline__ void gld_lds16(const void* g, void* l) {
    __builtin_amdgcn_global_load_lds((gas_ptr)g, (las_ptr)l, 16, 0, 0);
}

__device__ __forceinline__ ushort f2bf_u(float f) {
    uint32_t x = __float_as_uint(f);
    x += 0x7fff + ((x >> 16) & 1);   // RNE
    return (ushort)(x >> 16);
}

// ---------------- fused cast fp32 -> bf16 (7 arrays, 1 launch) ----------------
__global__ __launch_bounds__(256) void cast_all(
        const float* __restrict__ q, const float* __restrict__ k,
        const float* __restrict__ v, const float* __restrict__ Wq,
        const float* __restrict__ Wk, const float* __restrict__ Wv,
        const float* __restrict__ Wo,
        ushort* __restrict__ qb, ushort* __restrict__ kb, ushort* __restrict__ vb,
        ushort* __restrict__ Wqb, ushort* __restrict__ Wkb,
        ushort* __restrict__ Wvb, ushort* __restrict__ Wob) {
    int bid = blockIdx.x;
    const float* src; ushort* dst; int base;
    if      (bid <  4096) { src = q;  dst = qb;  base = bid; }
    else if (bid <  8192) { src = k;  dst = kb;  base = bid - 4096; }
    else if (bid < 12288) { src = v;  dst = vb;  base = bid - 8192; }
    else if (bid < 13312) { src = Wq; dst = Wqb; base = bid - 12288; }
    else if (bid < 14336) { src = Wk; dst = Wkb; base = bid - 13312; }
    else if (bid < 15360) { src = Wv; dst = Wvb; base = bid - 14336; }
    else                  { src = Wo; dst = Wob; base = bid - 15360; }
    int i = base * 1024 + threadIdx.x * 4;
    float4 f = *reinterpret_cast<const float4*>(src + i);
    ushort4 o;
    o.x = f2bf_u(f.x); o.y = f2bf_u(f.y); o.z = f2bf_u(f.z); o.w = f2bf_u(f.w);
    *reinterpret_cast<ushort4*>(dst + i) = o;
}

// ---------------- mask -> additive bias (fp32), written over dead qb region ----
__global__ __launch_bounds__(256) void mask2bias(
        const int* __restrict__ m, float* __restrict__ mb) {
    int i = (blockIdx.x * 256 + threadIdx.x) * 4;
    int4 mk = *reinterpret_cast<const int4*>(m + i);
    float4 o;
    o.x = mk.x ? 0.f : -1e9f;
    o.y = mk.y ? 0.f : -1e9f;
    o.z = mk.z ? 0.f : -1e9f;
    o.w = mk.w ? 0.f : -1e9f;
    *reinterpret_cast<float4*>(mb + i) = o;
}

// ---------------- GEMM: C[m][n] = sum_k A[m][k] * W[n][k] + bias[n] ----------------
// 64x128 tile, BK=32, 4 waves (2x2), wave-tile 32x64, acc 2x4 frags of 16x16x32 bf16.
template<int MODE>
__global__ __launch_bounds__(256) void gemm_bt(
        const ushort* __restrict__ A,   // M x K bf16 row-major
        const ushort* __restrict__ W,   // N x K bf16 row-major
        const float* __restrict__ bias, // N
        void* __restrict__ out, int M, int N, int K) {
    __shared__ ushort As[64 * 32];
    __shared__ ushort Bs[128 * 32];
    const int tid = threadIdx.x;
    const int w = tid >> 6, lane = tid & 63;
    const int lr = lane & 15, lg = lane >> 4;
    const int nTiles = N >> 7;
    const int nwg = gridDim.x;
    const int cpx = nwg >> 3;
    int lid = (blockIdx.x & 7) * cpx + (blockIdx.x >> 3);
    const int tM = (lid / nTiles) << 6;
    const int tN = (lid % nTiles) << 7;
    const int wr = (w >> 1) * 32, wc = (w & 1) * 64;

    f32x4 acc[2][4] = {};

    const int cA = w * 64 + lane;
    const int cB0 = w * 128 + lane;
    const int cB1 = w * 128 + 64 + lane;
    const ushort* gA  = A + (size_t)(tM + (cA  >> 2)) * K + (cA  & 3) * 8;
    const ushort* gB0 = W + (size_t)(tN + (cB0 >> 2)) * K + (cB0 & 3) * 8;
    const ushort* gB1 = W + (size_t)(tN + (cB1 >> 2)) * K + (cB1 & 3) * 8;
    ushort* lA  = As + w * 512;
    ushort* lB0 = Bs + w * 1024;
    ushort* lB1 = Bs + w * 1024 + 512;

    for (int k0 = 0; k0 < K; k0 += 32) {
        gld_lds16(gA  + k0, lA);
        gld_lds16(gB0 + k0, lB0);
        gld_lds16(gB1 + k0, lB1);
        __syncthreads();

        bf16x8 af[2], bfr[4];
#pragma unroll
        for (int i = 0; i < 2; i++)
            af[i] = *(const bf16x8*)(As + (wr + i * 16 + lr) * 32 + lg * 8);
#pragma unroll
        for (int i = 0; i < 4; i++)
            bfr[i] = *(const bf16x8*)(Bs + (wc + i * 16 + lr) * 32 + lg * 8);
#pragma unroll
        for (int mi = 0; mi < 2; mi++)
#pragma unroll
            for (int ni = 0; ni < 4; ni++)
                acc[mi][ni] = __builtin_amdgcn_mfma_f32_16x16x32_bf16(
                    af[mi], bfr[ni], acc[mi][ni], 0, 0, 0);
        __syncthreads();
    }

#pragma unroll
    for (int mi = 0; mi < 2; mi++) {
        const int row0 = tM + wr + mi * 16 + lg * 4;
#pragma unroll
        for (int ni = 0; ni < 4; ni++) {
            const int col = tN + wc + ni * 16 + lr;
            const float bv = bias[col];
#pragma unroll
            for (int r = 0; r < 4; r++) {
                float vv = acc[mi][ni][r] + bv;
                int m = row0 + r;
                if (MODE == 2) {
                    ((float*)out)[(size_t)m * N + col] = vv;
                } else {
                    int b = m >> 11, s = m & (SEQ - 1);
                    int h = col >> 6, d = col & (DK - 1);
                    if (MODE == 0)
                        ((ushort*)out)[(((size_t)(b * NHEADS + h) * SEQ + s) * DK) + d] = f2bf_u(vv);
                    else
                        ((ushort*)out)[(((size_t)(b * NHEADS + h) * DK + d) * SEQ) + s] = f2bf_u(vv);
                }
            }
        }
    }
}

// ---------------- attention: swapped-QK 32x32, in-register softmax ----------------
// log2-domain: p = exp2(fma(s, SCALE2, mbias) - m2).  K reg-double-buffered,
// V issued at body top / consumed at body end (T14 issue-early).
#define SCALE2 0.18033688011120542f   // 0.125 * log2(e)

__device__ __forceinline__ bf16x8 pack_pa(const float* p) {
    uint a, b, c, d;
    asm("v_cvt_pk_bf16_f32 %0, %1, %2" : "=v"(a) : "v"(p[0]), "v"(p[1]));
    asm("v_cvt_pk_bf16_f32 %0, %1, %2" : "=v"(b) : "v"(p[4]), "v"(p[5]));
    asm("v_cvt_pk_bf16_f32 %0, %1, %2" : "=v"(c) : "v"(p[2]), "v"(p[3]));
    asm("v_cvt_pk_bf16_f32 %0, %1, %2" : "=v"(d) : "v"(p[6]), "v"(p[7]));
    asm("v_permlane32_swap_b32 %0, %1" : "+v"(a), "+v"(b));
    asm("v_permlane32_swap_b32 %0, %1" : "+v"(c), "+v"(d));
    union { u32x4 u; bf16x8 h; } cv;
    cv.u = (u32x4){a, c, b, d};
    return cv.h;
}

__global__ __launch_bounds__(256) void attn_fwd32(
        const ushort* __restrict__ Qh, const ushort* __restrict__ Kh,
        const ushort* __restrict__ Vt, const float* __restrict__ mbias,
        ushort* __restrict__ ctx) {
    const int w = threadIdx.x >> 6;
    const int l = threadIdx.x & 63;
    const int q32 = l & 31, hi = l >> 5;

    int lid = (blockIdx.x & 7) * 64 + (blockIdx.x >> 3);
    const int qblk = lid & 15;
    const int bh = lid >> 4;
    const int b = bh >> 4, h = bh & 15;
    const int q0 = qblk * 128 + w * 32;

    const ushort* Qp  = Qh + (size_t)bh * SEQ * DK + (size_t)(q0 + q32) * DK + hi * 8;
    const ushort* Kp  = Kh + (size_t)bh * SEQ * DK + (size_t)q32 * DK + hi * 8;
    const ushort* Vp0 = Vt + (size_t)bh * DK * SEQ + (size_t)q32 * SEQ + hi * 8;
    const ushort* Vp1 = Vp0 + (size_t)32 * SEQ;
    const float* mrow = mbias + b * SEQ + hi * 4;

    bf16x8 qf[4];
#pragma unroll
    for (int dc = 0; dc < 4; dc++)
        qf[dc] = *(const bf16x8*)(Qp + dc * 16);

    f32x16 c0 = {}, c1 = {};
    float m2 = -1e30f, lrun = 0.f;

    bf16x8 ka[4], kb_[4];
#pragma unroll
    for (int dc = 0; dc < 4; dc++)
        ka[dc] = *(const bf16x8*)(Kp + dc * 16);

    auto body = [&](bf16x8 (&kc)[4], bf16x8 (&kn)[4], int t) {
        const int kv0 = t * 32;
        const int kvn = ((t + 1) & (NT - 1)) * 32;   // wraps to 0 on last (harmless)
        // prefetch K(t+1)
#pragma unroll
        for (int dc = 0; dc < 4; dc++)
            kn[dc] = *(const bf16x8*)(Kp + (size_t)kvn * DK + dc * 16);
        // issue V(t) early; consumed after softmax
        bf16x8 vc0 = *(const bf16x8*)(Vp0 + kv0);
        bf16x8 vc1 = *(const bf16x8*)(Vp0 + kv0 + 16);
        bf16x8 vc2 = *(const bf16x8*)(Vp1 + kv0);
        bf16x8 vc3 = *(const bf16x8*)(Vp1 + kv0 + 16);
        float4 mb[4];
#pragma unroll
        for (int g = 0; g < 4; g++)
            mb[g] = *reinterpret_cast<const float4*>(mrow + kv0 + g * 8);
        // QK^T (swapped) with current K regs
        f32x16 s = {};
#pragma unroll
        for (int dc = 0; dc < 4; dc++)
            s = __builtin_amdgcn_mfma_f32_32x32x16_bf16(kc[dc], qf[dc], s, 0, 0, 0);
        float p[16];
#pragma unroll
        for (int r = 0; r < 16; r++)
            p[r] = fmaf(s[r], SCALE2, reinterpret_cast<const float*>(&mb[r >> 2])[r & 3]);
        // tile max (tree -> v_max3 fusion) + cross-half
        float m01 = fmaxf(p[0], p[1]),   m23 = fmaxf(p[2], p[3]);
        float m45 = fmaxf(p[4], p[5]),   m67 = fmaxf(p[6], p[7]);
        float m89 = fmaxf(p[8], p[9]),   mab = fmaxf(p[10], p[11]);
        float mcd = fmaxf(p[12], p[13]), mef = fmaxf(p[14], p[15]);
        float pm = fmaxf(fmaxf(fmaxf(m01, m23), fmaxf(m45, m67)),
                         fmaxf(fmaxf(m89, mab), fmaxf(mcd, mef)));
        pm = fmaxf(pm, __shfl_xor(pm, 32));
        if (__any(pm - m2 > 8.0f)) {          // defer-max (T13)
            float mnew = fmaxf(m2, pm);
            float alpha = exp2f(m2 - mnew);
            m2 = mnew; lrun *= alpha;
#pragma unroll
            for (int r = 0; r < 16; r++) {
                float aT = __shfl(alpha, (r & 3) + 8 * (r >> 2) + 4 * hi);
                c0[r] *= aT; c1[r] *= aT;
            }
        }
        float rs = 0.f;
#pragma unroll
        for (int r = 0; r < 16; r++) { p[r] = exp2f(p[r] - m2); rs += p[r]; }
        rs += __shfl_xor(rs, 32);
        lrun += rs;
        bf16x8 pa0 = pack_pa(p);
        bf16x8 pa1 = pack_pa(p + 8);
        c0 = __builtin_amdgcn_mfma_f32_32x32x16_bf16(pa0, vc0, c0, 0, 0, 0);
        c1 = __builtin_amdgcn_mfma_f32_32x32x16_bf16(pa0, vc2, c1, 0, 0, 0);
        c0 = __builtin_amdgcn_mfma_f32_32x32x16_bf16(pa1, vc1, c0, 0, 0, 0);
        c1 = __builtin_amdgcn_mfma_f32_32x32x16_bf16(pa1, vc3, c1, 0, 0, 0);
    };

    for (int t = 0; t < NT; t += 2) {
        body(ka, kb_, t);
        body(kb_, ka, t + 1);
    }

    float rl = 1.0f / lrun;
#pragma unroll
    for (int r = 0; r < 16; r++) {
        int crow = (r & 3) + 8 * (r >> 2) + 4 * hi;
        float rlT = __shfl(rl, crow);
        int qq = q0 + crow;
        size_t base = (size_t)(b * SEQ + qq) * DMODEL + h * DK;
        ctx[base + q32]      = f2bf_u(c0[r] * rlT);
        ctx[base + 32 + q32] = f2bf_u(c1[r] * rlT);
    }
}

extern "C" void kernel_launch(void* const* d_in, const int* in_sizes, int n_in,
                              void* d_out, int out_size, void* d_ws, size_t ws_size,
                              hipStream_t stream) {
    const float* q    = (const float*)d_in[0];
    const float* k    = (const float*)d_in[1];
    const float* v    = (const float*)d_in[2];
    const int*   mask = (const int*)d_in[3];
    const float* Wq   = (const float*)d_in[4];
    const float* bq   = (const float*)d_in[5];
    const float* Wk   = (const float*)d_in[6];
    const float* bk   = (const float*)d_in[7];
    const float* Wv   = (const float*)d_in[8];
    const float* bv   = (const float*)d_in[9];
    const float* Wo   = (const float*)d_in[10];
    const float* bo   = (const float*)d_in[11];

    char* ws = (char*)d_ws;
    ushort* qb   = (ushort*)(ws + (size_t)0);
    ushort* kb   = (ushort*)(ws + ((size_t)8  << 20));
    ushort* vb   = (ushort*)(ws + ((size_t)16 << 20));
    ushort* Wqb  = (ushort*)(ws + ((size_t)24 << 20));
    ushort* Wkb  = (ushort*)(ws + ((size_t)26 << 20));
    ushort* Wvb  = (ushort*)(ws + ((size_t)28 << 20));
    ushort* Wob  = (ushort*)(ws + ((size_t)30 << 20));
    ushort* Qh   = (ushort*)(ws + ((size_t)32 << 20));
    ushort* Kh   = (ushort*)(ws + ((size_t)40 << 20));
    ushort* Vt   = (ushort*)(ws + ((size_t)48 << 20));
    ushort* ctxb = (ushort*)(ws + ((size_t)56 << 20));
    float*  mbias = (float*)(ws + (size_t)0);   // overlaps qb (dead after Q GEMM)

    cast_all<<<16384, 256, 0, stream>>>(q, k, v, Wq, Wk, Wv, Wo,
                                        qb, kb, vb, Wqb, Wkb, Wvb, Wob);

    const int M = BATCH * SEQ;
    const int gemmGrid = (M / 64) * (DMODEL / 128);   // 512
    gemm_bt<0><<<gemmGrid, 256, 0, stream>>>(qb, Wqb, bq, Qh, M, DMODEL, DMODEL);
    gemm_bt<0><<<gemmGrid, 256, 0, stream>>>(kb, Wkb, bk, Kh, M, DMODEL, DMODEL);
    gemm_bt<1><<<gemmGrid, 256, 0, stream>>>(vb, Wvb, bv, Vt, M, DMODEL, DMODEL);

    mask2bias<<<BATCH * SEQ / 1024, 256, 0, stream>>>(mask, mbias);

    attn_fwd32<<<BATCH * NHEADS * (SEQ / 128), 256, 0, stream>>>(Qh, Kh, Vt, mbias, ctxb);

    gemm_bt<2><<<gemmGrid, 256, 0, stream>>>(ctxb, Wob, bo, (void*)d_out, M, DMODEL, DMODEL);
}